// Round 13
// baseline (213.879 us; speedup 1.0000x reference)
//
#include <hip/hip_runtime.h>
#include <hip/hip_bf16.h>
#include <math.h>

#define B_N 8192
#define D_N 768
#define K_N 1000
#define NPAD 1024
#define M_TOP 30
#define ENT_THR 0.6f
#define EPS_N 1e-12f

typedef unsigned short u16;
typedef __attribute__((ext_vector_type(8))) short bf16x8;
typedef __attribute__((ext_vector_type(4))) float f32x4;

__device__ __forceinline__ u16 f2bf(float x) {
    __hip_bfloat16 h = __float2bfloat16(x);
    return *(u16*)&h;
}
__device__ __forceinline__ float bf2f(u16 u) {
    __hip_bfloat16 h;
    *(u16*)&h = u;
    return __bfloat162float(h);
}

__device__ __forceinline__ void gload16(const void* g, void* l) {
    __builtin_amdgcn_global_load_lds((const __attribute__((address_space(1))) void*)g,
                                     (__attribute__((address_space(3))) void*)l, 16, 0, 0);
}

// ---------------- prep z: rownorm inv + hi/lo bf16 split, one wave per row ----------------
__global__ __launch_bounds__(256) void prep_z_kernel(const float* __restrict__ z,
                                                     u16* __restrict__ zh,
                                                     u16* __restrict__ zl,
                                                     float* __restrict__ zinv) {
    int t = threadIdx.x;
    int lane = t & 63;
    int row = blockIdx.x * 4 + (t >> 6);
    const float* zr = z + (size_t)row * D_N;
    float4 v[3];
    float s = 0.f;
#pragma unroll
    for (int j = 0; j < 3; ++j) {
        v[j] = *(const float4*)(zr + j * 256 + lane * 4);
        s += v[j].x * v[j].x + v[j].y * v[j].y + v[j].z * v[j].z + v[j].w * v[j].w;
    }
#pragma unroll
    for (int off = 32; off; off >>= 1) s += __shfl_xor(s, off);
    if (lane == 0) zinv[row] = 1.0f / fmaxf(sqrtf(s), EPS_N);
#pragma unroll
    for (int j = 0; j < 3; ++j) {
        float4 w = v[j];
        u16 h0 = f2bf(w.x), h1 = f2bf(w.y), h2 = f2bf(w.z), h3 = f2bf(w.w);
        ushort4 hv = make_ushort4(h0, h1, h2, h3);
        ushort4 lv = make_ushort4(f2bf(w.x - bf2f(h0)), f2bf(w.y - bf2f(h1)),
                                  f2bf(w.z - bf2f(h2)), f2bf(w.w - bf2f(h3)));
        size_t o = (size_t)row * D_N + j * 256 + lane * 4;
        *(ushort4*)(zh + o) = hv;
        *(ushort4*)(zl + o) = lv;
    }
}

// ---------------- prep W: rownorm inv + bf16 hi, padded to NPAD rows ----------------
__global__ __launch_bounds__(256) void prep_w_kernel(const float* __restrict__ W,
                                                     u16* __restrict__ Wh,
                                                     float* __restrict__ winv) {
    int t = threadIdx.x;
    int lane = t & 63;
    int row = blockIdx.x * 4 + (t >> 6);
    if (row >= K_N) {
#pragma unroll
        for (int j = 0; j < 3; ++j)
            *(ushort4*)(Wh + (size_t)row * D_N + j * 256 + lane * 4) = make_ushort4(0, 0, 0, 0);
        return;
    }
    const float* wr = W + (size_t)row * D_N;
    float4 v[3];
    float s = 0.f;
#pragma unroll
    for (int j = 0; j < 3; ++j) {
        v[j] = *(const float4*)(wr + j * 256 + lane * 4);
        s += v[j].x * v[j].x + v[j].y * v[j].y + v[j].z * v[j].z + v[j].w * v[j].w;
    }
#pragma unroll
    for (int off = 32; off; off >>= 1) s += __shfl_xor(s, off);
    if (lane == 0) winv[row] = 1.0f / fmaxf(sqrtf(s), EPS_N);
#pragma unroll
    for (int j = 0; j < 3; ++j) {
        float4 w = v[j];
        ushort4 hv = make_ushort4(f2bf(w.x), f2bf(w.y), f2bf(w.z), f2bf(w.w));
        *(ushort4*)(Wh + (size_t)row * D_N + j * 256 + lane * 4) = hv;
    }
}

// ---------------- bf16 MFMA GEMM, 128x64 tile, 2-phase prefetch + T2 XOR-swizzle ----------------
// Tile 128(M)x64(N), BK=32, 4 waves (2Mx2N), per-wave 64x32 = 4x2 fragments.
// Grid 1024 blocks -> 3-4 blocks/CU resident: cross-block TLP hides per-block barrier drain.
// LDS swizzle (rule #21, both-sides): physical 16B-slot p = logical g ^ ((row%16)>>1 & 3).
// SPLIT=1: 3-term hi/lo product. Epilogue: optional bias[n], rowscale[m].
template <int SPLIT>
__global__ __launch_bounds__(256) void gemm_mfma(const u16* __restrict__ Ah,
                                                 const u16* __restrict__ Al,
                                                 const u16* __restrict__ Bh,
                                                 const u16* __restrict__ Bl,
                                                 const float* __restrict__ bias,
                                                 const float* __restrict__ rowscale,
                                                 float* __restrict__ C) {
    __shared__ __align__(16) u16 sA[2][128 * 32];
    __shared__ __align__(16) u16 sB[2][64 * 32];
    __shared__ __align__(16) u16 sAl[SPLIT ? 2 : 1][SPLIT ? 128 * 32 : 8];
    __shared__ __align__(16) u16 sBl[SPLIT ? 2 : 1][SPLIT ? 64 * 32 : 8];

    int t = threadIdx.x;
    int ln = t & 63, wv = t >> 6;
    int wr = wv >> 1, wc = wv & 1;
    int m0 = blockIdx.y * 128;
    int n0 = blockIdx.x * 64;

    f32x4 acc[4][2];
#pragma unroll
    for (int i = 0; i < 4; ++i)
#pragma unroll
        for (int j = 0; j < 2; ++j) acc[i][j] = (f32x4)0.f;

    // staging geometry: chunk c (1KB = 16 rows x 64B); lane covers 16B
    int srow = ln >> 2;            // 0..15 within chunk
    // pre-swizzled source column: slot (ln&3) holds logical block (ln&3)^((ln>>3)&3)
    int kc = (((ln & 3) ^ ((ln >> 3) & 3)) * 8);
    // fragment geometry (read side of the same involution)
    int kb = ((ln >> 4) * 16) ^ ((((ln & 15) >> 1) & 3) << 4);
    int fr_row = ln & 15;

    auto STAGE = [&](int p, int k0) {
        // A tile: 8 chunks (128 rows), wave wv covers chunks {wv, wv+4}
#pragma unroll
        for (int it = 0; it < 2; ++it) {
            int c = wv + it * 4;
            int row = c * 16 + srow;
            size_t ga = (size_t)(m0 + row) * D_N + k0 + kc;
            gload16(Ah + ga, (char*)sA[p] + c * 1024);
            if (SPLIT) gload16(Al + ga, (char*)sAl[p] + c * 1024);
        }
        // B tile: 4 chunks (64 rows), wave wv covers chunk wv
        {
            int c = wv;
            int row = c * 16 + srow;
            size_t gb = (size_t)(n0 + row) * D_N + k0 + kc;
            gload16(Bh + gb, (char*)sB[p] + c * 1024);
            if (SPLIT) gload16(Bl + gb, (char*)sBl[p] + c * 1024);
        }
    };

    constexpr int NT = D_N / 32;   // 24 K-tiles
    STAGE(0, 0);
    __syncthreads();
    int cur = 0;
    for (int tt = 0; tt < NT; ++tt) {
        if (tt + 1 < NT) STAGE(cur ^ 1, (tt + 1) * 32);   // prefetch overlaps compute below

        bf16x8 ah[4], bh[2], al[4], bl[2];
#pragma unroll
        for (int f = 0; f < 4; ++f) {
            int abyte = (wr * 64 + f * 16 + fr_row) * 64 + kb;
            ah[f] = *(const bf16x8*)((const char*)sA[cur] + abyte);
            if (SPLIT) al[f] = *(const bf16x8*)((const char*)sAl[cur] + abyte);
        }
#pragma unroll
        for (int f = 0; f < 2; ++f) {
            int bbyte = (wc * 32 + f * 16 + fr_row) * 64 + kb;
            bh[f] = *(const bf16x8*)((const char*)sB[cur] + bbyte);
            if (SPLIT) bl[f] = *(const bf16x8*)((const char*)sBl[cur] + bbyte);
        }
#pragma unroll
        for (int fr = 0; fr < 4; ++fr)
#pragma unroll
            for (int fc = 0; fc < 2; ++fc) {
                acc[fr][fc] = __builtin_amdgcn_mfma_f32_16x16x32_bf16(ah[fr], bh[fc], acc[fr][fc], 0, 0, 0);
                if (SPLIT) {
                    acc[fr][fc] = __builtin_amdgcn_mfma_f32_16x16x32_bf16(ah[fr], bl[fc], acc[fr][fc], 0, 0, 0);
                    acc[fr][fc] = __builtin_amdgcn_mfma_f32_16x16x32_bf16(al[fr], bh[fc], acc[fr][fc], 0, 0, 0);
                }
            }
        __syncthreads();   // drains prefetch (overlapped) + syncs buffer reuse
        cur ^= 1;
    }

    // epilogue: C/D layout col=lane&15, row=(lane>>4)*4+reg  [measured m89/m91]
    int lr4 = (ln >> 4) * 4;
    int lc = ln & 15;
#pragma unroll
    for (int fr = 0; fr < 4; ++fr) {
#pragma unroll
        for (int fc = 0; fc < 2; ++fc) {
            int gn = n0 + wc * 32 + fc * 16 + lc;
            if (gn >= K_N) continue;
            float bv = bias ? bias[gn] : 0.f;
#pragma unroll
            for (int r = 0; r < 4; ++r) {
                int gm = m0 + wr * 64 + fr * 16 + lr4 + r;
                float v = acc[fr][fc][r] + bv;
                if (rowscale) v *= rowscale[gm];
                C[(size_t)gm * K_N + gn] = v;
            }
        }
    }
}

// ---------------- per-row softmax entropy + argmax + fused keep/compact ----------------
__global__ __launch_bounds__(256) void row_entropy_kernel(const float* __restrict__ logits,
                                                          unsigned long long* __restrict__ recs,
                                                          int* __restrict__ cnt) {
    int row = blockIdx.x;
    int t = threadIdx.x;
    const float* lr = logits + (size_t)row * K_N;
    float v[4];
    float mx = -INFINITY; int am = K_N;
#pragma unroll
    for (int j = 0; j < 4; ++j) {
        int idx = j * 256 + t;
        float val = (idx < K_N) ? lr[idx] : -INFINITY;
        v[j] = val;
        if (val > mx) { mx = val; am = idx; }
    }
    __shared__ float sv[256];
    __shared__ int si[256];
    __shared__ float sw[256];
    sv[t] = mx; si[t] = am; __syncthreads();
    for (int st = 128; st > 0; st >>= 1) {
        if (t < st) {
            float v2 = sv[t + st]; int i2 = si[t + st];
            if (v2 > sv[t] || (v2 == sv[t] && i2 < si[t])) { sv[t] = v2; si[t] = i2; }
        }
        __syncthreads();
    }
    float rmx = sv[0]; int ram = si[0];
    __syncthreads();
    float s = 0.f, w = 0.f;
#pragma unroll
    for (int j = 0; j < 4; ++j) {
        int idx = j * 256 + t;
        if (idx < K_N) {
            float d = v[j] - rmx;
            float e = expf(d);
            s += e; w += d * e;
        }
    }
    sv[t] = s; sw[t] = w; __syncthreads();
    for (int st = 128; st > 0; st >>= 1) {
        if (t < st) { sv[t] += sv[t + st]; sw[t] += sw[t + st]; }
        __syncthreads();
    }
    if (t == 0) {
        float S = sv[0];
        float e = logf(S) - sw[0] / S;
        if (e <= ENT_THR) {
            int pos = atomicAdd(cnt, 1);
            unsigned long long key = ((unsigned long long)__float_as_uint(e) << 32) |
                                     ((unsigned long long)(unsigned)ram << 13) |
                                     (unsigned)row;
            recs[pos] = key;
        }
    }
}

// ---------------- per-class top-(M-1) smallest keys ----------------
__global__ __launch_bounds__(64) void select_topm_kernel(const unsigned long long* __restrict__ recs,
                                                         const int* __restrict__ cnt,
                                                         int* __restrict__ sel_ids,
                                                         int* __restrict__ n_sel) {
    int k = blockIdx.x;
    int lane = threadIdx.x;
    __shared__ unsigned long long top[M_TOP - 1];
    if (lane < M_TOP - 1) top[lane] = ~0ULL;
    __syncthreads();
    int n = *cnt;
    for (int base = 0; base < n; base += 64) {
        int i = base + lane;
        unsigned long long key = ~0ULL;
        bool match = false;
        if (i < n) {
            key = recs[i];
            match = ((int)((key >> 13) & 0x3FF) == k);
        }
        unsigned long long mball = __ballot(match);
        while (mball) {
            int b = __ffsll(mball) - 1;
            unsigned long long kv = __shfl(key, b);
            if (lane == 0) {
                if (kv < top[M_TOP - 2]) {
                    int pos = M_TOP - 2;
                    while (pos > 0 && top[pos - 1] > kv) { top[pos] = top[pos - 1]; --pos; }
                    top[pos] = kv;
                }
            }
            mball &= (mball - 1);
        }
    }
    __syncthreads();
    if (lane < M_TOP - 1) {
        unsigned long long kv = top[lane];
        sel_ids[k * (M_TOP - 1) + lane] = (kv == ~0ULL) ? -1 : (int)(kv & 0x1FFF);
    }
    unsigned long long vb = __ballot(lane < M_TOP - 1 && top[lane] != ~0ULL);
    if (lane == 0) n_sel[k] = (int)__popcll(vb);
}

// ---------------- centroid + normalize -> bf16 hi/lo, padded to NPAD rows ----------------
__global__ __launch_bounds__(256) void centroid_kernel(const float* __restrict__ W,
                                                       const float* __restrict__ winv,
                                                       const float* __restrict__ z,
                                                       const float* __restrict__ zinv,
                                                       const int* __restrict__ sel_ids,
                                                       const int* __restrict__ n_sel,
                                                       u16* __restrict__ Ch,
                                                       u16* __restrict__ Cl) {
    int k = blockIdx.x;
    int t = threadIdx.x;
    if (k >= K_N) {
#pragma unroll
        for (int j = 0; j < 3; ++j) {
            Ch[(size_t)k * D_N + j * 256 + t] = 0;
            Cl[(size_t)k * D_N + j * 256 + t] = 0;
        }
        return;
    }
    float acc[3];
    float wi = winv[k];
#pragma unroll
    for (int j = 0; j < 3; ++j) acc[j] = W[(size_t)k * D_N + j * 256 + t] * wi;
    int ns = n_sel[k];
    for (int s = 0; s < ns; ++s) {
        int id = sel_ids[k * (M_TOP - 1) + s];
        float sc = zinv[id];
#pragma unroll
        for (int j = 0; j < 3; ++j) acc[j] += z[(size_t)id * D_N + j * 256 + t] * sc;
    }
    float invc = 1.0f / (float)(1 + ns);
    float s2 = 0.f;
#pragma unroll
    for (int j = 0; j < 3; ++j) { acc[j] *= invc; s2 += acc[j] * acc[j]; }
    __shared__ float red[256];
    __shared__ float sinv;
    red[t] = s2; __syncthreads();
    for (int st = 128; st > 0; st >>= 1) {
        if (t < st) red[t] += red[t + st];
        __syncthreads();
    }
    if (t == 0) sinv = 1.0f / fmaxf(sqrtf(red[0]), EPS_N);
    __syncthreads();
    float iv = sinv;
#pragma unroll
    for (int j = 0; j < 3; ++j) {
        float v = acc[j] * iv;
        u16 h = f2bf(v);
        u16 l = f2bf(v - bf2f(h));
        Ch[(size_t)k * D_N + j * 256 + t] = h;
        Cl[(size_t)k * D_N + j * 256 + t] = l;
    }
}

extern "C" void kernel_launch(void* const* d_in, const int* in_sizes, int n_in,
                              void* d_out, int out_size, void* d_ws, size_t ws_size,
                              hipStream_t stream) {
    const float* z = (const float*)d_in[0];
    const float* W = (const float*)d_in[1];
    const float* b = (const float*)d_in[2];
    float* out = (float*)d_out;

    char* p = (char*)d_ws;
    auto alloc = [&](size_t bytes) { void* r = (void*)p; p += (bytes + 255) & ~(size_t)255; return r; };
    float* zinv = (float*)alloc(B_N * 4);
    float* winv = (float*)alloc(K_N * 4);
    unsigned long long* recs = (unsigned long long*)alloc(B_N * 8);
    int* cnt = (int*)alloc(4);
    int* n_sel = (int*)alloc(K_N * 4);
    int* sel_ids = (int*)alloc(K_N * (M_TOP - 1) * 4);
    u16* zh = (u16*)alloc((size_t)B_N * D_N * 2);
    u16* zl = (u16*)alloc((size_t)B_N * D_N * 2);
    u16* Wh = (u16*)alloc((size_t)NPAD * D_N * 2);
    u16* Ch = (u16*)alloc((size_t)NPAD * D_N * 2);
    u16* Cl = (u16*)alloc((size_t)NPAD * D_N * 2);

    hipMemsetAsync(cnt, 0, 4, stream);

    prep_z_kernel<<<B_N / 4, 256, 0, stream>>>(z, zh, zl, zinv);
    prep_w_kernel<<<NPAD / 4, 256, 0, stream>>>(W, Wh, winv);

    dim3 gg(NPAD / 64, B_N / 128);   // 16 x 64 = 1024 blocks -> 3-4 blocks/CU resident
    // GEMM1: logits = z@W^T + b, staged in d_out
    gemm_mfma<0><<<gg, 256, 0, stream>>>(zh, nullptr, Wh, nullptr, b, nullptr, out);

    row_entropy_kernel<<<B_N, 256, 0, stream>>>(out, recs, cnt);
    select_topm_kernel<<<K_N, 64, 0, stream>>>(recs, cnt, sel_ids, n_sel);
    centroid_kernel<<<NPAD, 256, 0, stream>>>(W, winv, z, zinv, sel_ids, n_sel, Ch, Cl);

    // GEMM2: out = diag(zinv) * (z @ Cn^T), 3-term bf16 split
    gemm_mfma<1><<<gg, 256, 0, stream>>>(zh, zl, Ch, Cl, nullptr, zinv, out);
}

// Round 14
// 167.303 us; speedup vs baseline: 1.2784x; 1.2784x over previous
//
#include <hip/hip_runtime.h>
#include <hip/hip_bf16.h>
#include <math.h>

#define B_N 8192
#define D_N 768
#define K_N 1000
#define NPAD 1024
#define M_TOP 30
#define ENT_THR 0.6f
#define EPS_N 1e-12f

typedef unsigned short u16;
typedef __attribute__((ext_vector_type(8))) _Float16 f16x8;
typedef __attribute__((ext_vector_type(4))) float f32x4;

__device__ __forceinline__ u16 f2h(float x) {
    _Float16 h = (_Float16)x;
    return *(u16*)&h;
}

__device__ __forceinline__ void gload16(const void* g, void* l) {
    __builtin_amdgcn_global_load_lds((const __attribute__((address_space(1))) void*)g,
                                     (__attribute__((address_space(3))) void*)l, 16, 0, 0);
}

// ---------------- prep z: rownorm inv + f16 convert, one wave per row ----------------
__global__ __launch_bounds__(256) void prep_z_kernel(const float* __restrict__ z,
                                                     u16* __restrict__ zh,
                                                     float* __restrict__ zinv) {
    int t = threadIdx.x;
    int lane = t & 63;
    int row = blockIdx.x * 4 + (t >> 6);
    const float* zr = z + (size_t)row * D_N;
    float4 v[3];
    float s = 0.f;
#pragma unroll
    for (int j = 0; j < 3; ++j) {
        v[j] = *(const float4*)(zr + j * 256 + lane * 4);
        s += v[j].x * v[j].x + v[j].y * v[j].y + v[j].z * v[j].z + v[j].w * v[j].w;
    }
#pragma unroll
    for (int off = 32; off; off >>= 1) s += __shfl_xor(s, off);
    if (lane == 0) zinv[row] = 1.0f / fmaxf(sqrtf(s), EPS_N);
#pragma unroll
    for (int j = 0; j < 3; ++j) {
        float4 w = v[j];
        ushort4 hv = make_ushort4(f2h(w.x), f2h(w.y), f2h(w.z), f2h(w.w));
        *(ushort4*)(zh + (size_t)row * D_N + j * 256 + lane * 4) = hv;
    }
}

// ---------------- prep W: rownorm inv + f16 convert, padded to NPAD rows ----------------
__global__ __launch_bounds__(256) void prep_w_kernel(const float* __restrict__ W,
                                                     u16* __restrict__ Wh,
                                                     float* __restrict__ winv) {
    int t = threadIdx.x;
    int lane = t & 63;
    int row = blockIdx.x * 4 + (t >> 6);
    if (row >= K_N) {
#pragma unroll
        for (int j = 0; j < 3; ++j)
            *(ushort4*)(Wh + (size_t)row * D_N + j * 256 + lane * 4) = make_ushort4(0, 0, 0, 0);
        return;
    }
    const float* wr = W + (size_t)row * D_N;
    float4 v[3];
    float s = 0.f;
#pragma unroll
    for (int j = 0; j < 3; ++j) {
        v[j] = *(const float4*)(wr + j * 256 + lane * 4);
        s += v[j].x * v[j].x + v[j].y * v[j].y + v[j].z * v[j].z + v[j].w * v[j].w;
    }
#pragma unroll
    for (int off = 32; off; off >>= 1) s += __shfl_xor(s, off);
    if (lane == 0) winv[row] = 1.0f / fmaxf(sqrtf(s), EPS_N);
#pragma unroll
    for (int j = 0; j < 3; ++j) {
        float4 w = v[j];
        ushort4 hv = make_ushort4(f2h(w.x), f2h(w.y), f2h(w.z), f2h(w.w));
        *(ushort4*)(Wh + (size_t)row * D_N + j * 256 + lane * 4) = hv;
    }
}

// ---------------- f16 MFMA GEMM, 128x128 tile (measured best), 2-phase prefetch + T2 swizzle ----
// Single-term f16: input rounding error ~1e-4 on unit-vector dots (below prior 4.9e-4 split error).
// LDS swizzle (rule #21, both-sides): physical 16B-slot p = logical g ^ ((row%16)>>1 & 3).
// Write side: LDS linear (global_load_lds), global SOURCE col pre-swizzled; read side XORs kb.
__global__ __launch_bounds__(256) void gemm_mfma(const u16* __restrict__ Ah,
                                                 const u16* __restrict__ Bh,
                                                 const float* __restrict__ bias,
                                                 const float* __restrict__ rowscale,
                                                 float* __restrict__ C) {
    __shared__ __align__(16) u16 sA[2][128 * 32];
    __shared__ __align__(16) u16 sB[2][128 * 32];

    int t = threadIdx.x;
    int ln = t & 63, wv = t >> 6;
    int wr = wv >> 1, wc = wv & 1;
    int m0 = blockIdx.y * 128;
    int n0 = blockIdx.x * 128;

    f32x4 acc[4][4];
#pragma unroll
    for (int i = 0; i < 4; ++i)
#pragma unroll
        for (int j = 0; j < 4; ++j) acc[i][j] = (f32x4)0.f;

    // staging geometry: chunk c (1KB = 16 rows x 64B); lane covers 16B
    int srow = ln >> 2;            // 0..15 within chunk
    // pre-swizzled source column: slot (ln&3) holds logical block (ln&3)^((ln>>3)&3)
    int kc = (((ln & 3) ^ ((ln >> 3) & 3)) * 8);
    // fragment geometry (read side of the same involution)
    int kb = ((ln >> 4) * 16) ^ ((((ln & 15) >> 1) & 3) << 4);
    int fr_row = ln & 15;

    auto STAGE = [&](int p, int k0) {
#pragma unroll
        for (int it = 0; it < 2; ++it) {
            int c = wv + it * 4;
            int row = c * 16 + srow;
            size_t ga = (size_t)(m0 + row) * D_N + k0 + kc;
            size_t gb = (size_t)(n0 + row) * D_N + k0 + kc;
            gload16(Ah + ga, (char*)sA[p] + c * 1024);
            gload16(Bh + gb, (char*)sB[p] + c * 1024);
        }
    };

    constexpr int NT = D_N / 32;   // 24 K-tiles
    STAGE(0, 0);
    __syncthreads();
    int cur = 0;
    for (int tt = 0; tt < NT; ++tt) {
        if (tt + 1 < NT) STAGE(cur ^ 1, (tt + 1) * 32);   // prefetch overlaps compute below

        f16x8 ah[4], bh[4];
#pragma unroll
        for (int f = 0; f < 4; ++f) {
            int abyte = (wr * 64 + f * 16 + fr_row) * 64 + kb;
            int bbyte = (wc * 64 + f * 16 + fr_row) * 64 + kb;
            ah[f] = *(const f16x8*)((const char*)sA[cur] + abyte);
            bh[f] = *(const f16x8*)((const char*)sB[cur] + bbyte);
        }
#pragma unroll
        for (int fr = 0; fr < 4; ++fr)
#pragma unroll
            for (int fc = 0; fc < 4; ++fc)
                acc[fr][fc] = __builtin_amdgcn_mfma_f32_16x16x32_f16(ah[fr], bh[fc], acc[fr][fc], 0, 0, 0);
        __syncthreads();   // drains prefetch (overlapped) + syncs buffer reuse
        cur ^= 1;
    }

    // epilogue: C/D layout col=lane&15, row=(lane>>4)*4+reg  [measured m89/m91]
    int lr4 = (ln >> 4) * 4;
    int lc = ln & 15;
#pragma unroll
    for (int fr = 0; fr < 4; ++fr) {
#pragma unroll
        for (int fc = 0; fc < 4; ++fc) {
            int gn = n0 + wc * 64 + fc * 16 + lc;
            if (gn >= K_N) continue;
            float bv = bias ? bias[gn] : 0.f;
#pragma unroll
            for (int r = 0; r < 4; ++r) {
                int gm = m0 + wr * 64 + fr * 16 + lr4 + r;
                float v = acc[fr][fc][r] + bv;
                if (rowscale) v *= rowscale[gm];
                C[(size_t)gm * K_N + gn] = v;
            }
        }
    }
}

// ---------------- per-row softmax entropy + argmax + fused keep/compact ----------------
__global__ __launch_bounds__(256) void row_entropy_kernel(const float* __restrict__ logits,
                                                          unsigned long long* __restrict__ recs,
                                                          int* __restrict__ cnt) {
    int row = blockIdx.x;
    int t = threadIdx.x;
    const float* lr = logits + (size_t)row * K_N;
    float v[4];
    float mx = -INFINITY; int am = K_N;
#pragma unroll
    for (int j = 0; j < 4; ++j) {
        int idx = j * 256 + t;
        float val = (idx < K_N) ? lr[idx] : -INFINITY;
        v[j] = val;
        if (val > mx) { mx = val; am = idx; }
    }
    __shared__ float sv[256];
    __shared__ int si[256];
    __shared__ float sw[256];
    sv[t] = mx; si[t] = am; __syncthreads();
    for (int st = 128; st > 0; st >>= 1) {
        if (t < st) {
            float v2 = sv[t + st]; int i2 = si[t + st];
            if (v2 > sv[t] || (v2 == sv[t] && i2 < si[t])) { sv[t] = v2; si[t] = i2; }
        }
        __syncthreads();
    }
    float rmx = sv[0]; int ram = si[0];
    __syncthreads();
    float s = 0.f, w = 0.f;
#pragma unroll
    for (int j = 0; j < 4; ++j) {
        int idx = j * 256 + t;
        if (idx < K_N) {
            float d = v[j] - rmx;
            float e = expf(d);
            s += e; w += d * e;
        }
    }
    sv[t] = s; sw[t] = w; __syncthreads();
    for (int st = 128; st > 0; st >>= 1) {
        if (t < st) { sv[t] += sv[t + st]; sw[t] += sw[t + st]; }
        __syncthreads();
    }
    if (t == 0) {
        float S = sv[0];
        float e = logf(S) - sw[0] / S;
        if (e <= ENT_THR) {
            int pos = atomicAdd(cnt, 1);
            unsigned long long key = ((unsigned long long)__float_as_uint(e) << 32) |
                                     ((unsigned long long)(unsigned)ram << 13) |
                                     (unsigned)row;
            recs[pos] = key;
        }
    }
}

// ---------------- per-class top-(M-1) smallest keys ----------------
__global__ __launch_bounds__(64) void select_topm_kernel(const unsigned long long* __restrict__ recs,
                                                         const int* __restrict__ cnt,
                                                         int* __restrict__ sel_ids,
                                                         int* __restrict__ n_sel) {
    int k = blockIdx.x;
    int lane = threadIdx.x;
    __shared__ unsigned long long top[M_TOP - 1];
    if (lane < M_TOP - 1) top[lane] = ~0ULL;
    __syncthreads();
    int n = *cnt;
    for (int base = 0; base < n; base += 64) {
        int i = base + lane;
        unsigned long long key = ~0ULL;
        bool match = false;
        if (i < n) {
            key = recs[i];
            match = ((int)((key >> 13) & 0x3FF) == k);
        }
        unsigned long long mball = __ballot(match);
        while (mball) {
            int b = __ffsll(mball) - 1;
            unsigned long long kv = __shfl(key, b);
            if (lane == 0) {
                if (kv < top[M_TOP - 2]) {
                    int pos = M_TOP - 2;
                    while (pos > 0 && top[pos - 1] > kv) { top[pos] = top[pos - 1]; --pos; }
                    top[pos] = kv;
                }
            }
            mball &= (mball - 1);
        }
    }
    __syncthreads();
    if (lane < M_TOP - 1) {
        unsigned long long kv = top[lane];
        sel_ids[k * (M_TOP - 1) + lane] = (kv == ~0ULL) ? -1 : (int)(kv & 0x1FFF);
    }
    unsigned long long vb = __ballot(lane < M_TOP - 1 && top[lane] != ~0ULL);
    if (lane == 0) n_sel[k] = (int)__popcll(vb);
}

// ---------------- centroid + normalize -> f16, padded to NPAD rows ----------------
__global__ __launch_bounds__(256) void centroid_kernel(const float* __restrict__ W,
                                                       const float* __restrict__ winv,
                                                       const float* __restrict__ z,
                                                       const float* __restrict__ zinv,
                                                       const int* __restrict__ sel_ids,
                                                       const int* __restrict__ n_sel,
                                                       u16* __restrict__ Ch) {
    int k = blockIdx.x;
    int t = threadIdx.x;
    if (k >= K_N) {
#pragma unroll
        for (int j = 0; j < 3; ++j) Ch[(size_t)k * D_N + j * 256 + t] = 0;
        return;
    }
    float acc[3];
    float wi = winv[k];
#pragma unroll
    for (int j = 0; j < 3; ++j) acc[j] = W[(size_t)k * D_N + j * 256 + t] * wi;
    int ns = n_sel[k];
    for (int s = 0; s < ns; ++s) {
        int id = sel_ids[k * (M_TOP - 1) + s];
        float sc = zinv[id];
#pragma unroll
        for (int j = 0; j < 3; ++j) acc[j] += z[(size_t)id * D_N + j * 256 + t] * sc;
    }
    float invc = 1.0f / (float)(1 + ns);
    float s2 = 0.f;
#pragma unroll
    for (int j = 0; j < 3; ++j) { acc[j] *= invc; s2 += acc[j] * acc[j]; }
    __shared__ float red[256];
    __shared__ float sinv;
    red[t] = s2; __syncthreads();
    for (int st = 128; st > 0; st >>= 1) {
        if (t < st) red[t] += red[t + st];
        __syncthreads();
    }
    if (t == 0) sinv = 1.0f / fmaxf(sqrtf(red[0]), EPS_N);
    __syncthreads();
    float iv = sinv;
#pragma unroll
    for (int j = 0; j < 3; ++j)
        Ch[(size_t)k * D_N + j * 256 + t] = f2h(acc[j] * iv);
}

extern "C" void kernel_launch(void* const* d_in, const int* in_sizes, int n_in,
                              void* d_out, int out_size, void* d_ws, size_t ws_size,
                              hipStream_t stream) {
    const float* z = (const float*)d_in[0];
    const float* W = (const float*)d_in[1];
    const float* b = (const float*)d_in[2];
    float* out = (float*)d_out;

    char* p = (char*)d_ws;
    auto alloc = [&](size_t bytes) { void* r = (void*)p; p += (bytes + 255) & ~(size_t)255; return r; };
    float* zinv = (float*)alloc(B_N * 4);
    float* winv = (float*)alloc(K_N * 4);
    unsigned long long* recs = (unsigned long long*)alloc(B_N * 8);
    int* cnt = (int*)alloc(4);
    int* n_sel = (int*)alloc(K_N * 4);
    int* sel_ids = (int*)alloc(K_N * (M_TOP - 1) * 4);
    u16* zh = (u16*)alloc((size_t)B_N * D_N * 2);
    u16* Wh = (u16*)alloc((size_t)NPAD * D_N * 2);
    u16* Ch = (u16*)alloc((size_t)NPAD * D_N * 2);

    hipMemsetAsync(cnt, 0, 4, stream);

    prep_z_kernel<<<B_N / 4, 256, 0, stream>>>(z, zh, zinv);
    prep_w_kernel<<<NPAD / 4, 256, 0, stream>>>(W, Wh, winv);

    dim3 gg(NPAD / 128, B_N / 128);   // 8 x 64 = 512 blocks, 128x128 tile (measured best)
    // GEMM1: logits = z@W^T + b, staged in d_out
    gemm_mfma<<<gg, 256, 0, stream>>>(zh, Wh, b, nullptr, out);

    row_entropy_kernel<<<B_N, 256, 0, stream>>>(out, recs, cnt);
    select_topm_kernel<<<K_N, 64, 0, stream>>>(recs, cnt, sel_ids, n_sel);
    centroid_kernel<<<NPAD, 256, 0, stream>>>(W, winv, z, zinv, sel_ids, n_sel, Ch);

    // GEMM2: out = diag(zinv) * (z @ Cn^T), single-term f16
    gemm_mfma<<<gg, 256, 0, stream>>>(zh, Ch, nullptr, zinv, out);
}